// Round 3
// baseline (404.031 us; speedup 1.0000x reference)
//
#include <hip/hip_runtime.h>
#include <hip/hip_fp16.h>

// ---------------- types ----------------
typedef _Float16 half8 __attribute__((ext_vector_type(8)));
typedef _Float16 half4v __attribute__((ext_vector_type(4)));
typedef float f32x4 __attribute__((ext_vector_type(4)));

#define GAS1(p) ((const __attribute__((address_space(1))) void*)(p))
#define LAS3(p) ((__attribute__((address_space(3))) void*)(p))

// Problem constants: B=8, N=1024, C=1024, H=16, D_HEAD=64, BH=128, M=8192
#define SCALE 0.125f
#define LOG2E 1.44269504088896340736f
#define RESCALE_THR 8.0f

// ---------------- f32 -> f16 conversion (vectorized) ----------------
__global__ void cvt_f32_f16(const float* __restrict__ in, _Float16* __restrict__ out) {
  int i = blockIdx.x * 256 + threadIdx.x;
  float4 f = reinterpret_cast<const float4*>(in)[i];
  half4v h;
  h[0] = (_Float16)f.x; h[1] = (_Float16)f.y;
  h[2] = (_Float16)f.z; h[3] = (_Float16)f.w;
  reinterpret_cast<half4v*>(out)[i] = h;
}

// ---------------- 128x128 GEMM, BK=64, C = A @ Bw^T (+bias) ----------------
// A: [M][K] row-major f16.  Bw: [N][K] row-major f16 (i.e. B-transposed input).
// EPI=0: Cf[m*Ndim+n] = acc + bias[n]  (fp32 out)
// EPI=1: qkv scatter: n -> (t,h,d); q scaled by SCALE; v written transposed.
// Grid remapped XCD-bijectively (nwg%8==0): A-panel-hot ordering per XCD.
template<int EPI>
__launch_bounds__(256, 2)
__global__ void gemm128(const _Float16* __restrict__ A, const _Float16* __restrict__ Bw,
                        const float* __restrict__ bias,
                        float* __restrict__ Cf,
                        _Float16* __restrict__ qo, _Float16* __restrict__ ko,
                        _Float16* __restrict__ vto,
                        int Kdim, int Ndim) {
  __shared__ alignas(128) _Float16 As[128 * 64];
  __shared__ alignas(128) _Float16 Bs[128 * 64];
  const int tid = threadIdx.x;
  const int w = tid >> 6, lane = tid & 63, lo = lane & 15, hi = lane >> 4;
  const int wr = w >> 1, wc = w & 1;

  // XCD-locality remap: consecutive pos within an XCD share the A panel.
  const int nby = gridDim.y;
  const int flat = blockIdx.x + gridDim.x * blockIdx.y;
  const int cpx = (gridDim.x * nby) >> 3;
  const int nf = (flat & 7) * cpx + (flat >> 3);
  const int tm0 = (nf / nby) * 128;
  const int tn0 = (nf % nby) * 128;

  f32x4 acc[4][4] = {};

  for (int k0 = 0; k0 < Kdim; k0 += 64) {
    __syncthreads();  // previous compute done before overwrite
#pragma unroll
    for (int r = 0; r < 4; ++r) {
      // dest linear, source inverse-swizzled (rule 21).
      int o = r * 4096 + w * 1024 + lane * 16;
      int row = o >> 7;
      int kk = ((o & 127) ^ ((row & 7) << 4)) >> 1;
      __builtin_amdgcn_global_load_lds(GAS1(A + (size_t)(tm0 + row) * Kdim + k0 + kk),
                                       LAS3((char*)As + r * 4096 + w * 1024), 16, 0, 0);
      __builtin_amdgcn_global_load_lds(GAS1(Bw + (size_t)(tn0 + row) * Kdim + k0 + kk),
                                       LAS3((char*)Bs + r * 4096 + w * 1024), 16, 0, 0);
    }
    __syncthreads();  // compiler drains vmcnt before barrier
#pragma unroll
    for (int s = 0; s < 2; ++s) {
      half8 af[4], bf[4];
#pragma unroll
      for (int i = 0; i < 4; ++i) {
        int arow = wr * 64 + i * 16 + lo;
        int abyte = (arow << 7) + ((hi * 16 + s * 64) ^ ((arow & 7) << 4));
        af[i] = *reinterpret_cast<const half8*>((const char*)As + abyte);
        int brow = wc * 64 + i * 16 + lo;
        int bbyte = (brow << 7) + ((hi * 16 + s * 64) ^ ((brow & 7) << 4));
        bf[i] = *reinterpret_cast<const half8*>((const char*)Bs + bbyte);
      }
      __builtin_amdgcn_s_setprio(1);
#pragma unroll
      for (int i = 0; i < 4; ++i)
#pragma unroll
        for (int j = 0; j < 4; ++j)
          acc[i][j] = __builtin_amdgcn_mfma_f32_16x16x32_f16(af[i], bf[j], acc[i][j], 0, 0, 0);
      __builtin_amdgcn_s_setprio(0);
    }
  }

  // Epilogue.  D layout: row = hi*4 + reg, col = lo (m89-verified).
  if (EPI == 0) {
#pragma unroll
    for (int i = 0; i < 4; ++i) {
      const int m0 = tm0 + wr * 64 + i * 16 + hi * 4;
#pragma unroll
      for (int j = 0; j < 4; ++j) {
        const int n = tn0 + wc * 64 + j * 16 + lo;
        const float bj = bias[n];
#pragma unroll
        for (int r = 0; r < 4; ++r)
          Cf[(size_t)(m0 + r) * Ndim + n] = acc[i][j][r] + bj;
      }
    }
  } else {
    const int t = tn0 >> 10;  // block-uniform: 1024 % 128 == 0
#pragma unroll
    for (int i = 0; i < 4; ++i) {
      const int m0 = tm0 + wr * 64 + i * 16 + hi * 4;
      const int b = m0 >> 10;
      const int nr = m0 & 1023;
#pragma unroll
      for (int j = 0; j < 4; ++j) {
        const int n = tn0 + wc * 64 + j * 16 + lo;
        const float bj = bias[n];
        const int h = (n >> 6) & 15;
        const int d = n & 63;
        const size_t hb = ((size_t)(b * 16 + h)) << 16;  // *65536
        if (t == 0) {
#pragma unroll
          for (int r = 0; r < 4; ++r)
            qo[hb + (size_t)(nr + r) * 64 + d] = (_Float16)((acc[i][j][r] + bj) * SCALE);
        } else if (t == 1) {
#pragma unroll
          for (int r = 0; r < 4; ++r)
            ko[hb + (size_t)(nr + r) * 64 + d] = (_Float16)(acc[i][j][r] + bj);
        } else {
          half4v v4;
#pragma unroll
          for (int r = 0; r < 4; ++r) v4[r] = (_Float16)(acc[i][j][r] + bj);
          // V transposed: vt[bh][d][n]; nr % 4 == 0 -> 8B aligned
          *reinterpret_cast<half4v*>(vto + hb + (size_t)d * 1024 + nr) = v4;
        }
      }
    }
  }
}

// ---------------- flash attention v3 ----------------
// q,k: [BH][1024][64] f16 (q pre-scaled).  vt: [BH][64][1024] f16.
// z out: [B][1024][C] f16.
// 1D grid (1024 blocks), XCD-locality map: all 8 q-tiles of a head + 16 heads
// per XCD -> per-XCD K/V working set = 4 MB = L2.  4 waves/block, 32 q-rows
// per wave; K/V LDS double-buffered (XOR-swizzled).  Defer-max softmax (T13)
// + per-lane partial row-sum (reduced once at the end).
__launch_bounds__(256, 4)
__global__ void attn_kernel(const _Float16* __restrict__ q, const _Float16* __restrict__ kb,
                            const _Float16* __restrict__ vt, _Float16* __restrict__ z) {
  __shared__ alignas(128) _Float16 Ks[2][64 * 64];  // 16 KB
  __shared__ alignas(128) _Float16 Vs[2][64 * 64];  // 16 KB  (rows = d, cols = n)
  __shared__ alignas(128) _Float16 P[4][16 * 64];   // 8 KB, per-wave swizzled
  const int tid = threadIdx.x;
  const int w = tid >> 6, lane = tid & 63, lo = lane & 15, hi = lane >> 4;

  const int bid = blockIdx.x;
  const int pos = bid >> 3;
  const int bh = (bid & 7) * 16 + (pos >> 3);  // 16 heads per XCD
  const int qr0 = (pos & 7) * 128 + w * 32;    // 8 q-tiles of a head on one XCD
  const size_t base = (size_t)bh << 16;        // *65536

  auto stage = [&](int buf, int kt) {
#pragma unroll
    for (int p = 0; p < 2; ++p) {
      int o = p * 4096 + w * 1024 + lane * 16;
      int row = o >> 7;
      int kk = ((o & 127) ^ ((row & 7) << 4)) >> 1;
      __builtin_amdgcn_global_load_lds(GAS1(kb + base + (size_t)(kt + row) * 64 + kk),
                                       LAS3((char*)&Ks[buf][0] + p * 4096 + w * 1024), 16, 0, 0);
      __builtin_amdgcn_global_load_lds(GAS1(vt + base + (size_t)row * 1024 + kt + kk),
                                       LAS3((char*)&Vs[buf][0] + p * 4096 + w * 1024), 16, 0, 0);
    }
  };

  stage(0, 0);

  half8 qf[2][2];
#pragma unroll
  for (int rg = 0; rg < 2; ++rg)
#pragma unroll
    for (int s = 0; s < 2; ++s)
      qf[rg][s] = *reinterpret_cast<const half8*>(
          q + base + (size_t)(qr0 + rg * 16 + lo) * 64 + s * 32 + hi * 8);

  f32x4 zacc[2][4] = {};
  float m_r[2][4], l_r[2][4];
#pragma unroll
  for (int rg = 0; rg < 2; ++rg)
#pragma unroll
    for (int r = 0; r < 4; ++r) { m_r[rg][r] = -1e30f; l_r[rg][r] = 0.f; }

  _Float16* Pw = &P[w][0];
  __syncthreads();

  int buf = 0;
  for (int kt = 0; kt < 1024; kt += 64) {
    if (kt + 64 < 1024) stage(buf ^ 1, kt + 64);
    const char* Kb = (const char*)&Ks[buf][0];
    const char* Vb = (const char*)&Vs[buf][0];

#pragma unroll
    for (int rg = 0; rg < 2; ++rg) {
      // S = Q K^T : 16 q-rows x 64 k-cols
      f32x4 sacc[4];
      half8 bK[4][2];
#pragma unroll
      for (int c = 0; c < 4; ++c)
#pragma unroll
        for (int s = 0; s < 2; ++s) {
          int row = c * 16 + lo;
          bK[c][s] = *reinterpret_cast<const half8*>(
              Kb + (row << 7) + ((s * 64 + hi * 16) ^ ((row & 7) << 4)));
        }
      __builtin_amdgcn_s_setprio(1);
#pragma unroll
      for (int c = 0; c < 4; ++c) {
        sacc[c] = f32x4{0.f, 0.f, 0.f, 0.f};
#pragma unroll
        for (int s = 0; s < 2; ++s)
          sacc[c] = __builtin_amdgcn_mfma_f32_16x16x32_f16(qf[rg][s], bK[c][s], sacc[c], 0, 0, 0);
      }
      __builtin_amdgcn_s_setprio(0);

      // online softmax: defer-max (THR=8) + per-lane partial l.
#pragma unroll
      for (int r = 0; r < 4; ++r) {
        float t = fmaxf(fmaxf(sacc[0][r], sacc[1][r]), fmaxf(sacc[2][r], sacc[3][r]));
        if (!__all(t <= m_r[rg][r] + RESCALE_THR)) {
          // full per-row (per hi-group) max reduce + rescale
          t = fmaxf(t, __shfl_xor(t, 1));
          t = fmaxf(t, __shfl_xor(t, 2));
          t = fmaxf(t, __shfl_xor(t, 4));
          t = fmaxf(t, __shfl_xor(t, 8));
          float mn = fmaxf(m_r[rg][r], t);
          float alpha = exp2f((m_r[rg][r] - mn) * LOG2E);
          m_r[rg][r] = mn;
          l_r[rg][r] *= alpha;
#pragma unroll
          for (int v = 0; v < 4; ++v) zacc[rg][v][r] *= alpha;
        }
        const float ml = m_r[rg][r] * LOG2E;
        float psum = 0.f;
#pragma unroll
        for (int c = 0; c < 4; ++c) {
          float p = exp2f(sacc[c][r] * LOG2E - ml);
          sacc[c][r] = p;
          psum += p;
        }
        l_r[rg][r] += psum;  // per-lane partial; reduced after the k-loop
      }

      // P -> LDS (swizzled), then read back in A-fragment layout
#pragma unroll
      for (int c = 0; c < 4; ++c)
#pragma unroll
        for (int r = 0; r < 4; ++r) {
          int row = hi * 4 + r;
          int byteoff = (row << 7) + ((c * 32 + lo * 2) ^ ((row & 7) << 4));
          *reinterpret_cast<_Float16*>((char*)Pw + byteoff) = (_Float16)sacc[c][r];
        }
      // PV: zacc += P @ V   (B-operand from LDS Vt tile)
#pragma unroll
      for (int s = 0; s < 2; ++s) {
        int pbyte = (lo << 7) + ((hi * 16 + s * 64) ^ ((lo & 7) << 4));
        half8 pf = *reinterpret_cast<const half8*>((const char*)Pw + pbyte);
        half8 bV[4];
#pragma unroll
        for (int v = 0; v < 4; ++v) {
          int row = v * 16 + lo;
          bV[v] = *reinterpret_cast<const half8*>(
              Vb + (row << 7) + ((s * 64 + hi * 16) ^ ((row & 7) << 4)));
        }
        __builtin_amdgcn_s_setprio(1);
#pragma unroll
        for (int v = 0; v < 4; ++v)
          zacc[rg][v] = __builtin_amdgcn_mfma_f32_16x16x32_f16(pf, bV[v], zacc[rg][v], 0, 0, 0);
        __builtin_amdgcn_s_setprio(0);
      }
    }
    __syncthreads();  // drains vmcnt(0): next buffer staged & all reads done
    buf ^= 1;
  }

  // finalize: reduce per-lane partial l across the 16 lo lanes, then store z
  const int b = bh >> 4, h = bh & 15;
#pragma unroll
  for (int rg = 0; rg < 2; ++rg)
#pragma unroll
    for (int r = 0; r < 4; ++r) {
      float l = l_r[rg][r];
      l += __shfl_xor(l, 1);
      l += __shfl_xor(l, 2);
      l += __shfl_xor(l, 4);
      l += __shfl_xor(l, 8);
      const float rl = 1.0f / l;
      const int qrow = qr0 + rg * 16 + hi * 4 + r;
#pragma unroll
      for (int v = 0; v < 4; ++v)
        z[((size_t)b * 1024 + qrow) * 1024 + h * 64 + v * 16 + lo] = (_Float16)(zacc[rg][v][r] * rl);
    }
}

// ---------------- launch ----------------
extern "C" void kernel_launch(void* const* d_in, const int* in_sizes, int n_in,
                              void* d_out, int out_size, void* d_ws, size_t ws_size,
                              hipStream_t stream) {
  const float* x      = (const float*)d_in[0];
  const float* qkv_w  = (const float*)d_in[1];
  const float* qkv_b  = (const float*)d_in[2];
  const float* proj_w = (const float*)d_in[3];
  const float* proj_b = (const float*)d_in[4];
  float* out = (float*)d_out;

  _Float16* ws    = (_Float16*)d_ws;
  _Float16* xb    = ws;                 // 8388608
  _Float16* wqkv  = ws + 8388608;       // 3145728
  _Float16* wproj = ws + 11534336;      // 1048576
  _Float16* qb    = ws + 12582912;      // 8388608  [BH][1024][64]
  _Float16* kbb   = ws + 20971520;      // 8388608  [BH][1024][64]
  _Float16* vtb   = ws + 29360128;      // 8388608  [BH][64][1024]
  _Float16* zb    = ws + 37748736;      // 8388608  [8192][1024]

  cvt_f32_f16<<<8192, 256, 0, stream>>>(x, xb);
  cvt_f32_f16<<<3072, 256, 0, stream>>>(qkv_w, wqkv);
  cvt_f32_f16<<<1024, 256, 0, stream>>>(proj_w, wproj);

  gemm128<1><<<dim3(64, 24), 256, 0, stream>>>(xb, wqkv, qkv_b, nullptr,
                                               qb, kbb, vtb, 1024, 3072);
  attn_kernel<<<1024, 256, 0, stream>>>(qb, kbb, vtb, zb);
  gemm128<0><<<dim3(64, 8), 256, 0, stream>>>(zb, wproj, proj_b, out,
                                              nullptr, nullptr, nullptr, 1024, 1024);
}

// Round 4
// 245.481 us; speedup vs baseline: 1.6459x; 1.6459x over previous
//
#include <hip/hip_runtime.h>
#include <hip/hip_fp16.h>

// ---------------- types ----------------
typedef _Float16 half8 __attribute__((ext_vector_type(8)));
typedef _Float16 half4v __attribute__((ext_vector_type(4)));
typedef float f32x4 __attribute__((ext_vector_type(4)));

#define GAS1(p) ((const __attribute__((address_space(1))) void*)(p))
#define LAS3(p) ((__attribute__((address_space(3))) void*)(p))

// Problem constants: B=8, N=1024, C=1024, H=16, D_HEAD=64, BH=128, M=8192
#define SCALE 0.125f
#define LOG2E 1.44269504088896340736f
#define RESCALE_THR 8.0f

// ---------------- f32 -> f16 conversion (vectorized) ----------------
__global__ void cvt_f32_f16(const float* __restrict__ in, _Float16* __restrict__ out) {
  int i = blockIdx.x * 256 + threadIdx.x;
  float4 f = reinterpret_cast<const float4*>(in)[i];
  half4v h;
  h[0] = (_Float16)f.x; h[1] = (_Float16)f.y;
  h[2] = (_Float16)f.z; h[3] = (_Float16)f.w;
  reinterpret_cast<half4v*>(out)[i] = h;
}

// ---------------- 128x128 GEMM, BK=64, C = A @ Bw^T (+bias) ----------------
// A: [M][K] row-major f16.  Bw: [N][K] row-major f16 (i.e. B-transposed input).
// EPI=0: Cf[m*Ndim+n] = acc + bias[n]  (fp32 out)
// EPI=1: qkv scatter: n -> (t,h,d); q scaled by SCALE; v written transposed.
template<int EPI>
__launch_bounds__(256, 2)
__global__ void gemm128(const _Float16* __restrict__ A, const _Float16* __restrict__ Bw,
                        const float* __restrict__ bias,
                        float* __restrict__ Cf,
                        _Float16* __restrict__ qo, _Float16* __restrict__ ko,
                        _Float16* __restrict__ vto,
                        int Kdim, int Ndim) {
  __shared__ alignas(128) _Float16 As[128 * 64];
  __shared__ alignas(128) _Float16 Bs[128 * 64];
  const int tid = threadIdx.x;
  const int w = tid >> 6, lane = tid & 63, lo = lane & 15, hi = lane >> 4;
  const int wr = w >> 1, wc = w & 1;
  const int tm0 = blockIdx.x * 128;
  const int tn0 = blockIdx.y * 128;

  f32x4 acc[4][4] = {};

  for (int k0 = 0; k0 < Kdim; k0 += 64) {
    __syncthreads();  // previous compute done before overwrite
#pragma unroll
    for (int r = 0; r < 4; ++r) {
      // dest linear, source inverse-swizzled (rule 21).
      int o = r * 4096 + w * 1024 + lane * 16;
      int row = o >> 7;
      int kk = ((o & 127) ^ ((row & 7) << 4)) >> 1;
      __builtin_amdgcn_global_load_lds(GAS1(A + (size_t)(tm0 + row) * Kdim + k0 + kk),
                                       LAS3((char*)As + r * 4096 + w * 1024), 16, 0, 0);
      __builtin_amdgcn_global_load_lds(GAS1(Bw + (size_t)(tn0 + row) * Kdim + k0 + kk),
                                       LAS3((char*)Bs + r * 4096 + w * 1024), 16, 0, 0);
    }
    __syncthreads();  // compiler drains vmcnt before barrier
#pragma unroll
    for (int s = 0; s < 2; ++s) {
      half8 af[4], bf[4];
#pragma unroll
      for (int i = 0; i < 4; ++i) {
        int arow = wr * 64 + i * 16 + lo;
        int abyte = (arow << 7) + ((hi * 16 + s * 64) ^ ((arow & 7) << 4));
        af[i] = *reinterpret_cast<const half8*>((const char*)As + abyte);
        int brow = wc * 64 + i * 16 + lo;
        int bbyte = (brow << 7) + ((hi * 16 + s * 64) ^ ((brow & 7) << 4));
        bf[i] = *reinterpret_cast<const half8*>((const char*)Bs + bbyte);
      }
#pragma unroll
      for (int i = 0; i < 4; ++i)
#pragma unroll
        for (int j = 0; j < 4; ++j)
          acc[i][j] = __builtin_amdgcn_mfma_f32_16x16x32_f16(af[i], bf[j], acc[i][j], 0, 0, 0);
    }
  }

  // Epilogue.  D layout: row = hi*4 + reg, col = lo (m89-verified).
  if (EPI == 0) {
#pragma unroll
    for (int i = 0; i < 4; ++i) {
      const int m0 = tm0 + wr * 64 + i * 16 + hi * 4;
#pragma unroll
      for (int j = 0; j < 4; ++j) {
        const int n = tn0 + wc * 64 + j * 16 + lo;
        const float bj = bias[n];
#pragma unroll
        for (int r = 0; r < 4; ++r)
          Cf[(size_t)(m0 + r) * Ndim + n] = acc[i][j][r] + bj;
      }
    }
  } else {
    const int t = tn0 >> 10;  // block-uniform: 1024 % 128 == 0
#pragma unroll
    for (int i = 0; i < 4; ++i) {
      const int m0 = tm0 + wr * 64 + i * 16 + hi * 4;
      const int b = m0 >> 10;
      const int nr = m0 & 1023;
#pragma unroll
      for (int j = 0; j < 4; ++j) {
        const int n = tn0 + wc * 64 + j * 16 + lo;
        const float bj = bias[n];
        const int h = (n >> 6) & 15;
        const int d = n & 63;
        const size_t hb = ((size_t)(b * 16 + h)) << 16;  // *65536
        if (t == 0) {
#pragma unroll
          for (int r = 0; r < 4; ++r)
            qo[hb + (size_t)(nr + r) * 64 + d] = (_Float16)((acc[i][j][r] + bj) * SCALE);
        } else if (t == 1) {
#pragma unroll
          for (int r = 0; r < 4; ++r)
            ko[hb + (size_t)(nr + r) * 64 + d] = (_Float16)(acc[i][j][r] + bj);
        } else {
          half4v v4;
#pragma unroll
          for (int r = 0; r < 4; ++r) v4[r] = (_Float16)(acc[i][j][r] + bj);
          // V transposed: vt[bh][d][n]; nr % 4 == 0 -> 8B aligned
          *reinterpret_cast<half4v*>(vto + hb + (size_t)d * 1024 + nr) = v4;
        }
      }
    }
  }
}

// ---------------- flash attention v4 (swapped-operand) ----------------
// q,k: [BH][1024][64] f16 (q pre-scaled).  vt: [BH][64][1024] f16.
// z out: [B][1024][C] f16.  Grid dim3(8,128) as R2 (measured-good locality).
// S^T = mfma(K,Q): per-lane softmax state (lane's lo = q-row), packed P
// writes (4x ds_write_b64/rg).  Z^T = mfma(V,P): lane-local rescale, packed
// 8B z-stores.  K-fragments hoisted (rg-invariant).  Defer-max (T13, THR=8).
__launch_bounds__(256, 4)
__global__ void attn_kernel(const _Float16* __restrict__ q, const _Float16* __restrict__ kb,
                            const _Float16* __restrict__ vt, _Float16* __restrict__ z) {
  __shared__ alignas(128) _Float16 Ks[2][64 * 64];  // 16 KB
  __shared__ alignas(128) _Float16 Vs[2][64 * 64];  // 16 KB  (rows = d, cols = n)
  __shared__ alignas(128) _Float16 P[4][16 * 64];   // 8 KB, per-wave swizzled
  const int tid = threadIdx.x;
  const int w = tid >> 6, lane = tid & 63, lo = lane & 15, hi = lane >> 4;
  const int bh = blockIdx.y;
  const int qr0 = blockIdx.x * 128 + w * 32;
  const size_t base = (size_t)bh << 16;  // *65536

  // stage one 64x64 K-tile and Vt-tile into LDS buffer `buf` (rule 21:
  // linear dest, inverse-swizzled source; reads below apply the swizzle).
  auto stage = [&](int buf, int kt) {
#pragma unroll
    for (int p = 0; p < 2; ++p) {
      int o = p * 4096 + w * 1024 + lane * 16;
      int row = o >> 7;
      int kk = ((o & 127) ^ ((row & 7) << 4)) >> 1;
      __builtin_amdgcn_global_load_lds(GAS1(kb + base + (size_t)(kt + row) * 64 + kk),
                                       LAS3((char*)&Ks[buf][0] + p * 4096 + w * 1024), 16, 0, 0);
      __builtin_amdgcn_global_load_lds(GAS1(vt + base + (size_t)row * 1024 + kt + kk),
                                       LAS3((char*)&Vs[buf][0] + p * 4096 + w * 1024), 16, 0, 0);
    }
  };

  stage(0, 0);

  half8 qf[2][2];  // B-fragment: lane lo = q-row qr0+rg*16+lo, k-slice s*32+hi*8
#pragma unroll
  for (int rg = 0; rg < 2; ++rg)
#pragma unroll
    for (int s = 0; s < 2; ++s)
      qf[rg][s] = *reinterpret_cast<const half8*>(
          q + base + (size_t)(qr0 + rg * 16 + lo) * 64 + s * 32 + hi * 8);

  f32x4 zacc[2][4] = {};        // Z^T: zacc[rg][v][r] = Z[q=lo][d=16v+4hi+r]
  float m_s[2] = {-1e30f, -1e30f};
  float l_s[2] = {0.f, 0.f};

  char* Pw = (char*)&P[w][0];
  __syncthreads();

  int buf = 0;
  for (int kt = 0; kt < 1024; kt += 64) {
    if (kt + 64 < 1024) stage(buf ^ 1, kt + 64);
    const char* Kb = (const char*)&Ks[buf][0];
    const char* Vb = (const char*)&Vs[buf][0];

    // ---- S^T = mfma(K, Q): sacc[rg][c][r] = S[q=lo][k=16c+4hi+r] ----
    f32x4 sacc[2][4];
#pragma unroll
    for (int rg = 0; rg < 2; ++rg)
#pragma unroll
      for (int c = 0; c < 4; ++c) sacc[rg][c] = f32x4{0.f, 0.f, 0.f, 0.f};
#pragma unroll
    for (int c = 0; c < 4; ++c) {
      const int row = c * 16 + lo;
      half8 bK0 = *reinterpret_cast<const half8*>(
          Kb + (row << 7) + ((hi * 16) ^ ((row & 7) << 4)));
      half8 bK1 = *reinterpret_cast<const half8*>(
          Kb + (row << 7) + ((64 + hi * 16) ^ ((row & 7) << 4)));
      __builtin_amdgcn_s_setprio(1);
#pragma unroll
      for (int rg = 0; rg < 2; ++rg) {
        sacc[rg][c] = __builtin_amdgcn_mfma_f32_16x16x32_f16(bK0, qf[rg][0], sacc[rg][c], 0, 0, 0);
        sacc[rg][c] = __builtin_amdgcn_mfma_f32_16x16x32_f16(bK1, qf[rg][1], sacc[rg][c], 0, 0, 0);
      }
      __builtin_amdgcn_s_setprio(0);
    }

#pragma unroll
    for (int rg = 0; rg < 2; ++rg) {
      // ---- per-lane online softmax (q-row = lo), defer-max ----
      float tmax = fmaxf(
          fmaxf(fmaxf(fmaxf(sacc[rg][0][0], sacc[rg][0][1]), fmaxf(sacc[rg][0][2], sacc[rg][0][3])),
                fmaxf(fmaxf(sacc[rg][1][0], sacc[rg][1][1]), fmaxf(sacc[rg][1][2], sacc[rg][1][3]))),
          fmaxf(fmaxf(fmaxf(sacc[rg][2][0], sacc[rg][2][1]), fmaxf(sacc[rg][2][2], sacc[rg][2][3])),
                fmaxf(fmaxf(sacc[rg][3][0], sacc[rg][3][1]), fmaxf(sacc[rg][3][2], sacc[rg][3][3]))));
      if (!__all(tmax <= m_s[rg] + RESCALE_THR)) {
        float t2 = fmaxf(tmax, __shfl_xor(tmax, 16));
        t2 = fmaxf(t2, __shfl_xor(t2, 32));          // row-true max over all hi-replicas
        float mn = fmaxf(m_s[rg], t2);
        float alpha = exp2f((m_s[rg] - mn) * LOG2E);
        m_s[rg] = mn;
        l_s[rg] *= alpha;
#pragma unroll
        for (int v = 0; v < 4; ++v)
#pragma unroll
          for (int u = 0; u < 4; ++u) zacc[rg][v][u] *= alpha;
      }
      const float ml = m_s[rg] * LOG2E;
      float psum = 0.f;
#pragma unroll
      for (int c = 0; c < 4; ++c)
#pragma unroll
        for (int u = 0; u < 4; ++u) {
          float p = exp2f(sacc[rg][c][u] * LOG2E - ml);
          sacc[rg][c][u] = p;
          psum += p;
        }
      l_s[rg] += psum;  // per-lane partial (this hi-replica's 16 cols)

      // ---- packed P write: P[q=lo][k=16c+4hi+u], 4x ds_write_b64 ----
#pragma unroll
      for (int c = 0; c < 4; ++c) {
        half4v p4;
#pragma unroll
        for (int u = 0; u < 4; ++u) p4[u] = (_Float16)sacc[rg][c][u];
        int byteoff = (lo << 7) + ((c * 32 + hi * 8) ^ ((lo & 7) << 4));
        *reinterpret_cast<half4v*>(Pw + byteoff) = p4;
      }

      // ---- Z^T += mfma(V, P) ----
#pragma unroll
      for (int s = 0; s < 2; ++s) {
        int pbyte = (lo << 7) + ((hi * 16 + s * 64) ^ ((lo & 7) << 4));
        half8 pf = *reinterpret_cast<const half8*>((const char*)Pw + pbyte);
        half8 bV[4];
#pragma unroll
        for (int v = 0; v < 4; ++v) {
          int row = v * 16 + lo;
          bV[v] = *reinterpret_cast<const half8*>(
              Vb + (row << 7) + ((s * 64 + hi * 16) ^ ((row & 7) << 4)));
        }
        __builtin_amdgcn_s_setprio(1);
#pragma unroll
        for (int v = 0; v < 4; ++v)
          zacc[rg][v] = __builtin_amdgcn_mfma_f32_16x16x32_f16(bV[v], pf, zacc[rg][v], 0, 0, 0);
        __builtin_amdgcn_s_setprio(0);
      }
    }
    __syncthreads();  // drains vmcnt(0): next buffer staged & all reads done
    buf ^= 1;
  }

  // finalize: reduce per-lane partial l across hi-replicas, packed 8B stores
  const int b = bh >> 4, h = bh & 15;
#pragma unroll
  for (int rg = 0; rg < 2; ++rg) {
    float l = l_s[rg];
    l += __shfl_xor(l, 16);
    l += __shfl_xor(l, 32);
    const float rl = 1.0f / l;
    const int qrow = qr0 + rg * 16 + lo;
#pragma unroll
    for (int v = 0; v < 4; ++v) {
      half4v o;
#pragma unroll
      for (int u = 0; u < 4; ++u) o[u] = (_Float16)(zacc[rg][v][u] * rl);
      *reinterpret_cast<half4v*>(
          z + ((size_t)b * 1024 + qrow) * 1024 + h * 64 + v * 16 + hi * 4) = o;
    }
  }
}

// ---------------- launch ----------------
extern "C" void kernel_launch(void* const* d_in, const int* in_sizes, int n_in,
                              void* d_out, int out_size, void* d_ws, size_t ws_size,
                              hipStream_t stream) {
  const float* x      = (const float*)d_in[0];
  const float* qkv_w  = (const float*)d_in[1];
  const float* qkv_b  = (const float*)d_in[2];
  const float* proj_w = (const float*)d_in[3];
  const float* proj_b = (const float*)d_in[4];
  float* out = (float*)d_out;

  _Float16* ws    = (_Float16*)d_ws;
  _Float16* xb    = ws;                 // 8388608
  _Float16* wqkv  = ws + 8388608;       // 3145728
  _Float16* wproj = ws + 11534336;      // 1048576
  _Float16* qb    = ws + 12582912;      // 8388608  [BH][1024][64]
  _Float16* kbb   = ws + 20971520;      // 8388608  [BH][1024][64]
  _Float16* vtb   = ws + 29360128;      // 8388608  [BH][64][1024]
  _Float16* zb    = ws + 37748736;      // 8388608  [8192][1024]

  cvt_f32_f16<<<8192, 256, 0, stream>>>(x, xb);
  cvt_f32_f16<<<3072, 256, 0, stream>>>(qkv_w, wqkv);
  cvt_f32_f16<<<1024, 256, 0, stream>>>(proj_w, wproj);

  gemm128<1><<<dim3(64, 24), 256, 0, stream>>>(xb, wqkv, qkv_b, nullptr,
                                               qb, kbb, vtb, 1024, 3072);
  attn_kernel<<<dim3(8, 128), 256, 0, stream>>>(qb, kbb, vtb, zb);
  gemm128<0><<<dim3(64, 8), 256, 0, stream>>>(zb, wproj, proj_b, out,
                                              nullptr, nullptr, nullptr, 1024, 1024);
}